// Round 12
// baseline (892.424 us; speedup 1.0000x reference)
//
#include <hip/hip_runtime.h>
#include <hip/hip_bf16.h>

// Problem constants
#define BB 4
#define LL 900
#define DMODEL 256
#define DSTATE 16
#define DINNER 512
#define DTRANK 16
#define BL (BB*LL)          // 3600
#define NC 64               // scan chunks (4 of len 15, 60 of len 14)
#define GRID 512            // co-resident blocks (2/CU via launch_bounds)

typedef __bf16 bf16x8 __attribute__((ext_vector_type(8)));
typedef __bf16 bf16x4 __attribute__((ext_vector_type(4)));
typedef float f32x4 __attribute__((ext_vector_type(4)));

__device__ __forceinline__ float silu_f(float v) { return v / (1.f + __expf(-v)); }

#define N_HID  (BL*DMODEL)             // 921600
#define N_WIN  (2*DINNER*DMODEL)       // 262144
#define N_WXP  (48*DINNER)             // 24576
#define N_WOUT (DMODEL*2*DINNER)       // 262144
#define N_TOT  (N_HID+N_WIN+N_WXP+N_WOUT)

struct MegaParams {
    const float *hidden, *Win, *Wxp, *Wdt, *bdt, *AlogF, *AlogB, *Df, *Db;
    const float *Wglob, *bglob, *Wgate, *bgate, *Wout;
    float *out;
    __bf16 *xh, *xl; float *z_silu, *dtBC, *dtb;
    __bf16 *yh, *yl;
    float *partial, *ymean, *t1, *gbuf;
    __bf16 *hh, *hl, *wih, *wil, *wxh, *wxl, *woh, *wol;
    float *Pbuf, *Qbuf;
    unsigned *ctr;
};

__global__ void init_ctrs(unsigned* ctr)
{
    if (threadIdx.x < 16) ctr[threadIdx.x] = 0u;
}

// software grid barrier: valid because GRID blocks are guaranteed co-resident
// (launch_bounds(256,2) -> >=2 blocks/CU; 512 = 2*256). Release/acquire at
// agent scope makes prior writes visible across XCD L2s.
__device__ __forceinline__ void gridbar(unsigned* ctr, int k)
{
    __syncthreads();
    if (threadIdx.x == 0) {
        __threadfence();
        __hip_atomic_fetch_add(&ctr[k], 1u, __ATOMIC_ACQ_REL, __HIP_MEMORY_SCOPE_AGENT);
        while (__hip_atomic_load(&ctr[k], __ATOMIC_ACQUIRE, __HIP_MEMORY_SCOPE_AGENT) < GRID)
            __builtin_amdgcn_s_sleep(2);
    }
    __syncthreads();
}

__launch_bounds__(256, 2)
__global__ void mega(MegaParams P)
{
    __shared__ char smem_raw[24576];
    const int tid = threadIdx.x, blk = blockIdx.x;
    const int gtid = blk * 256 + tid;
    const int gwave = gtid >> 6;
    const int lane = tid & 63, q = lane >> 4, r = lane & 15;

    // ---- P0: hi/lo split of hidden + weights ----
    for (int idx = gtid; idx < N_TOT; idx += GRID * 256) {
        const float* src; __bf16 *oh, *ol; int off;
        if (idx < N_HID)                        { src = P.hidden; oh = P.hh;  ol = P.hl;  off = idx; }
        else if (idx < N_HID+N_WIN)             { src = P.Win;    oh = P.wih; ol = P.wil; off = idx - N_HID; }
        else if (idx < N_HID+N_WIN+N_WXP)       { src = P.Wxp;    oh = P.wxh; ol = P.wxl; off = idx - N_HID - N_WIN; }
        else                                    { src = P.Wout;   oh = P.woh; ol = P.wol; off = idx - N_HID - N_WIN - N_WXP; }
        float v = src[off];
        __bf16 h = (__bf16)v;
        oh[off] = h; ol[off] = (__bf16)(v - (float)h);
    }
    gridbar(P.ctr, 0);

    // ---- P1: gemm1 xz = hidden @ W_in^T, fused silu (2400 wave-tiles) ----
    {
        constexpr int WM = 3, WN = 2, K = 256, nk = K >> 5;
        constexpr int ntN = (2 * DINNER) / (16 * WN);  // 32
        for (int u = gwave; u < (BL / 48) * ntN; u += GRID * 4) {
            int tm = u / ntN, tn = u % ntN;
            const bf16x8 *ArH[WM], *ArL[WM], *BrH[WN], *BrL[WN];
            #pragma unroll
            for (int mi = 0; mi < WM; ++mi) {
                size_t row = (size_t)(tm * 48 + mi * 16 + r) * K;
                ArH[mi] = (const bf16x8*)(P.hh + row); ArL[mi] = (const bf16x8*)(P.hl + row);
            }
            #pragma unroll
            for (int ni = 0; ni < WN; ++ni) {
                size_t row = (size_t)(tn * 32 + ni * 16 + r) * K;
                BrH[ni] = (const bf16x8*)(P.wih + row); BrL[ni] = (const bf16x8*)(P.wil + row);
            }
            f32x4 acc[WM][WN];
            #pragma unroll
            for (int mi = 0; mi < WM; ++mi)
                #pragma unroll
                for (int ni = 0; ni < WN; ++ni) acc[mi][ni] = (f32x4){0.f,0.f,0.f,0.f};
            #pragma unroll
            for (int kk = 0; kk < nk; ++kk) {
                int idx = kk * 4 + q;
                bf16x8 a_h[WM], a_l[WM], b_h[WN], b_l[WN];
                #pragma unroll
                for (int mi = 0; mi < WM; ++mi) { a_h[mi] = ArH[mi][idx]; a_l[mi] = ArL[mi][idx]; }
                #pragma unroll
                for (int ni = 0; ni < WN; ++ni) { b_h[ni] = BrH[ni][idx]; b_l[ni] = BrL[ni][idx]; }
                #pragma unroll
                for (int mi = 0; mi < WM; ++mi)
                    #pragma unroll
                    for (int ni = 0; ni < WN; ++ni) {
                        acc[mi][ni] = __builtin_amdgcn_mfma_f32_16x16x32_bf16(a_h[mi], b_h[ni], acc[mi][ni], 0, 0, 0);
                        acc[mi][ni] = __builtin_amdgcn_mfma_f32_16x16x32_bf16(a_h[mi], b_l[ni], acc[mi][ni], 0, 0, 0);
                        acc[mi][ni] = __builtin_amdgcn_mfma_f32_16x16x32_bf16(a_l[mi], b_h[ni], acc[mi][ni], 0, 0, 0);
                    }
            }
            #pragma unroll
            for (int mi = 0; mi < WM; ++mi)
                #pragma unroll
                for (int ni = 0; ni < WN; ++ni) {
                    int col = tn * 32 + ni * 16 + r;
                    #pragma unroll
                    for (int i = 0; i < 4; ++i) {
                        int row = tm * 48 + mi * 16 + q * 4 + i;
                        float s = silu_f(acc[mi][ni][i]);
                        if (col < DINNER) {
                            __bf16 h = (__bf16)s;
                            P.xh[(size_t)row * DINNER + col] = h;
                            P.xl[(size_t)row * DINNER + col] = (__bf16)(s - (float)h);
                        } else {
                            P.z_silu[(size_t)row * DINNER + (col - DINNER)] = s;
                        }
                    }
                }
        }
    }
    gridbar(P.ctr, 1);

    // ---- P2: gemm2 + dt (225 block-tiles) ----
    if (blk < 225) {
        constexpr int WN = 3, K = 512, KSL = 128, nk = KSL >> 5;
        float (*lds)[768] = reinterpret_cast<float(*)[768]>(smem_raw);
        int tm = blk, wv = tid >> 6, kOff = wv * KSL;
        const bf16x8* ArH = (const bf16x8*)(P.xh + (size_t)(tm * 16 + r) * K + kOff);
        const bf16x8* ArL = (const bf16x8*)(P.xl + (size_t)(tm * 16 + r) * K + kOff);
        const bf16x8 *BrH[WN], *BrL[WN];
        #pragma unroll
        for (int ni = 0; ni < WN; ++ni) {
            size_t row = (size_t)(ni * 16 + r) * K + kOff;
            BrH[ni] = (const bf16x8*)(P.wxh + row); BrL[ni] = (const bf16x8*)(P.wxl + row);
        }
        f32x4 acc[WN];
        #pragma unroll
        for (int ni = 0; ni < WN; ++ni) acc[ni] = (f32x4){0.f,0.f,0.f,0.f};
        #pragma unroll
        for (int kk = 0; kk < nk; ++kk) {
            int idx = kk * 4 + q;
            bf16x8 a_h = ArH[idx], a_l = ArL[idx];
            bf16x8 b_h[WN], b_l[WN];
            #pragma unroll
            for (int ni = 0; ni < WN; ++ni) { b_h[ni] = BrH[ni][idx]; b_l[ni] = BrL[ni][idx]; }
            #pragma unroll
            for (int ni = 0; ni < WN; ++ni) {
                acc[ni] = __builtin_amdgcn_mfma_f32_16x16x32_bf16(a_h, b_h[ni], acc[ni], 0, 0, 0);
                acc[ni] = __builtin_amdgcn_mfma_f32_16x16x32_bf16(a_h, b_l[ni], acc[ni], 0, 0, 0);
                acc[ni] = __builtin_amdgcn_mfma_f32_16x16x32_bf16(a_l, b_h[ni], acc[ni], 0, 0, 0);
            }
        }
        #pragma unroll
        for (int ni = 0; ni < WN; ++ni) {
            int col = ni * 16 + r;
            #pragma unroll
            for (int i = 0; i < 4; ++i)
                lds[wv][(q * 4 + i) * 48 + col] = acc[ni][i];
        }
        __syncthreads();
        for (int e = tid; e < 16 * 48; e += 256) {
            float s = lds[0][e] + lds[1][e] + lds[2][e] + lds[3][e];
            lds[0][e] = s;
            int row = e / 48, col = e % 48;
            P.dtBC[(size_t)(tm * 16 + row) * 48 + col] = s;
        }
        __syncthreads();
        for (int it = 0; it < 32; ++it) {
            int e = tid + it * 256;
            int row = e >> 9, d = e & 511;
            const float* wr = P.Wdt + (size_t)d * DTRANK;
            float s = P.bdt[d];
            #pragma unroll
            for (int k = 0; k < DTRANK; ++k) s = fmaf(lds[0][row * 48 + k], wr[k], s);
            P.dtb[(size_t)(tm * 16 + row) * DINNER + d] = (s > 15.f) ? s : __logf(1.f + __expf(s));
        }
    }
    gridbar(P.ctr, 2);

    // ---- P3: scan pass1 (2048 virtual 128-thread units; d-coalesced) ----
    for (int v = blk * 2 + (tid >> 7); v < 2048; v += GRID * 2) {
        int vt = tid & 127;
        int dgrp = v & 3, c = (v >> 2) & 63, dir = (v >> 8) & 1, b = v >> 9;
        int d = dgrp * 128 + vt;
        const float* Alog = dir ? P.AlogB : P.AlogF;
        float a2[DSTATE];
        #pragma unroll
        for (int n = 0; n < DSTATE; ++n) a2[n] = -__expf(Alog[d * DSTATE + n]) * 1.44269504f;
        float h[DSTATE];
        #pragma unroll
        for (int n = 0; n < DSTATE; ++n) h[n] = 0.f;
        float sdt = 0.f;
        int len = 14 + (c < 4 ? 1 : 0);
        int st  = 14 * c + (c < 4 ? c : 4);
        for (int il = 0; il < len; ++il) {
            int i = st + il;
            int l = dir ? (LL - 1 - i) : i;
            size_t base = (size_t)b * LL + l;
            float dtv = P.dtb[base * DINNER + d];
            float u = (float)P.xh[base * DINNER + d] + (float)P.xl[base * DINNER + d];
            float du = dtv * u;
            const f32x4* Bp = (const f32x4*)(P.dtBC + base * 48 + DTRANK);
            f32x4 Bq[4];
            #pragma unroll
            for (int j = 0; j < 4; ++j) Bq[j] = Bp[j];
            sdt += dtv;
            #pragma unroll
            for (int n = 0; n < DSTATE; ++n)
                h[n] = fmaf(exp2f(dtv * a2[n]), h[n], du * Bq[n >> 2][n & 3]);
        }
        size_t o = (((size_t)(b * 2 + dir) * NC + c) * DSTATE) * DINNER + d;
        #pragma unroll
        for (int n = 0; n < DSTATE; ++n) {
            P.Pbuf[o + (size_t)n * DINNER] = exp2f(sdt * a2[n]);
            P.Qbuf[o + (size_t)n * DINNER] = h[n];
        }
    }
    gridbar(P.ctr, 3);

    // ---- P4: stitch (in place: H0 overwrites Pbuf) ----
    if (gtid < 65536) {
        int bd = gtid >> 13, rem = gtid & 8191;
        size_t base = (size_t)bd * NC * 8192 + rem;
        float H = 0.f;
        for (int cb = 0; cb < NC; cb += 16) {
            float Pv[16], Qv[16];
            #pragma unroll
            for (int j = 0; j < 16; ++j) {
                size_t o = base + (size_t)(cb + j) * 8192;
                Pv[j] = P.Pbuf[o]; Qv[j] = P.Qbuf[o];
            }
            #pragma unroll
            for (int j = 0; j < 16; ++j) {
                P.Pbuf[base + (size_t)(cb + j) * 8192] = H;
                H = fmaf(Pv[j], H, Qv[j]);
            }
        }
    }
    gridbar(P.ctr, 4);

    // ---- P5: scan pass3 (emit y hi/lo + per-chunk mean partials) ----
    for (int v = blk * 2 + (tid >> 7); v < 2048; v += GRID * 2) {
        int vt = tid & 127;
        int dgrp = v & 3, c = (v >> 2) & 63, dir = (v >> 8) & 1, b = v >> 9;
        int d = dgrp * 128 + vt;
        const float* Alog = dir ? P.AlogB : P.AlogF;
        float a2[DSTATE];
        #pragma unroll
        for (int n = 0; n < DSTATE; ++n) a2[n] = -__expf(Alog[d * DSTATE + n]) * 1.44269504f;
        float Dd = dir ? P.Db[d] : P.Df[d];
        size_t o = (((size_t)(b * 2 + dir) * NC + c) * DSTATE) * DINNER + d;
        float h[DSTATE];
        #pragma unroll
        for (int n = 0; n < DSTATE; ++n) h[n] = P.Pbuf[o + (size_t)n * DINNER];
        float ysum = 0.f;
        int len = 14 + (c < 4 ? 1 : 0);
        int st  = 14 * c + (c < 4 ? c : 4);
        for (int il = 0; il < len; ++il) {
            int i = st + il;
            int l = dir ? (LL - 1 - i) : i;
            size_t base = (size_t)b * LL + l;
            float dtv = P.dtb[base * DINNER + d];
            float u = (float)P.xh[base * DINNER + d] + (float)P.xl[base * DINNER + d];
            float du = dtv * u;
            const f32x4* Bp = (const f32x4*)(P.dtBC + base * 48 + DTRANK);
            f32x4 Bq[4], Cq[4];
            #pragma unroll
            for (int j = 0; j < 4; ++j) Bq[j] = Bp[j];
            #pragma unroll
            for (int j = 0; j < 4; ++j) Cq[j] = Bp[4 + j];
            float p = 0.f;
            #pragma unroll
            for (int n = 0; n < DSTATE; ++n) {
                h[n] = fmaf(exp2f(dtv * a2[n]), h[n], du * Bq[n >> 2][n & 3]);
                p = fmaf(h[n], Cq[n >> 2][n & 3], p);
            }
            float zg = P.z_silu[base * DINNER + d];
            float yv = (p + Dd * u) * zg;
            __bf16 hv = (__bf16)yv;
            size_t yo = base * (2 * DINNER) + dir * DINNER + d;
            P.yh[yo] = hv;
            P.yl[yo] = (__bf16)(yv - (float)hv);
            ysum += yv;
        }
        P.partial[((size_t)b * NC + c) * 1024 + dir * DINNER + d] = ysum;
    }
    gridbar(P.ctr, 5);

    // ---- P6: mean over chunks ----
    if (gtid < 4096) {
        int b = gtid >> 10, ch = gtid & 1023;
        float s = 0.f;
        #pragma unroll 8
        for (int c = 0; c < NC; ++c) s += P.partial[((size_t)b * NC + c) * 1024 + ch];
        P.ymean[gtid] = s / (float)LL;
    }
    gridbar(P.ctr, 6);

    // ---- P7: gemv1 (4096 wave-units) ----
    for (int u = gwave; u < 4096; u += GRID * 4) {
        int b = u >> 10, j = u & 1023;
        const float* wr = P.Wglob + (size_t)j * 1024;
        const float* vr = P.ymean + (size_t)b * 1024;
        float s = 0.f;
        for (int k = lane; k < 1024; k += 64) s = fmaf(vr[k], wr[k], s);
        #pragma unroll
        for (int o2 = 32; o2; o2 >>= 1) s += __shfl_xor(s, o2);
        if (lane == 0) P.t1[u] = s + P.bglob[j];
    }
    gridbar(P.ctr, 7);

    // ---- P8: gemv2 + sigmoid ----
    for (int u = gwave; u < 4096; u += GRID * 4) {
        int b = u >> 10, j = u & 1023;
        const float* wr = P.Wgate + (size_t)j * 1024;
        const float* vr = P.t1 + (size_t)b * 1024;
        float s = 0.f;
        for (int k = lane; k < 1024; k += 64) s = fmaf(vr[k], wr[k], s);
        #pragma unroll
        for (int o2 = 32; o2; o2 >>= 1) s += __shfl_xor(s, o2);
        if (lane == 0) P.gbuf[u] = 1.f / (1.f + __expf(-(s + P.bgate[j])));
    }
    gridbar(P.ctr, 8);

    // ---- P9: y *= g (hi/lo in place, 4 elems/thread) ----
    for (int idx = gtid; idx < BL * 1024 / 4; idx += GRID * 256) {
        int e = idx * 4;
        int ch = e & 1023;
        int b = (e >> 10) / LL;
        bf16x4 hv = reinterpret_cast<bf16x4*>(P.yh)[idx];
        bf16x4 lv = reinterpret_cast<bf16x4*>(P.yl)[idx];
        f32x4 gv = *(const f32x4*)(P.gbuf + b * 1024 + ch);
        #pragma unroll
        for (int j = 0; j < 4; ++j) {
            float v = ((float)hv[j] + (float)lv[j]) * gv[j];
            __bf16 h = (__bf16)v;
            hv[j] = h; lv[j] = (__bf16)(v - (float)h);
        }
        reinterpret_cast<bf16x4*>(P.yh)[idx] = hv;
        reinterpret_cast<bf16x4*>(P.yl)[idx] = lv;
    }
    gridbar(P.ctr, 9);

    // ---- P10: gemm8 out = y @ W_out^T (300 block-tiles, KS=2 LDS-combined) ----
    if (blk < 300) {
        constexpr int WM = 3, WN = 2, K = 1024, KSL = 512, nk = KSL >> 5;
        constexpr int N = DMODEL, ntN = N / (16 * WN);
        float (*l8)[1536] = reinterpret_cast<float(*)[1536]>(smem_raw);
        int wv = tid >> 6;
        int tLoc = wv >> 1, ks = wv & 1;
        int tIdx = blk * 2 + tLoc;
        int tm = tIdx / ntN, tn = tIdx % ntN;
        int kOff = ks * KSL;
        const bf16x8 *ArH[WM], *ArL[WM], *BrH[WN], *BrL[WN];
        #pragma unroll
        for (int mi = 0; mi < WM; ++mi) {
            size_t row = (size_t)(tm * 48 + mi * 16 + r) * K + kOff;
            ArH[mi] = (const bf16x8*)(P.yh + row); ArL[mi] = (const bf16x8*)(P.yl + row);
        }
        #pragma unroll
        for (int ni = 0; ni < WN; ++ni) {
            size_t row = (size_t)(tn * 32 + ni * 16 + r) * K + kOff;
            BrH[ni] = (const bf16x8*)(P.woh + row); BrL[ni] = (const bf16x8*)(P.wol + row);
        }
        f32x4 acc[WM][WN];
        #pragma unroll
        for (int mi = 0; mi < WM; ++mi)
            #pragma unroll
            for (int ni = 0; ni < WN; ++ni) acc[mi][ni] = (f32x4){0.f,0.f,0.f,0.f};
        #pragma unroll
        for (int kk = 0; kk < nk; ++kk) {
            int idx = kk * 4 + q;
            bf16x8 a_h[WM], a_l[WM], b_h[WN], b_l[WN];
            #pragma unroll
            for (int mi = 0; mi < WM; ++mi) { a_h[mi] = ArH[mi][idx]; a_l[mi] = ArL[mi][idx]; }
            #pragma unroll
            for (int ni = 0; ni < WN; ++ni) { b_h[ni] = BrH[ni][idx]; b_l[ni] = BrL[ni][idx]; }
            #pragma unroll
            for (int mi = 0; mi < WM; ++mi)
                #pragma unroll
                for (int ni = 0; ni < WN; ++ni) {
                    acc[mi][ni] = __builtin_amdgcn_mfma_f32_16x16x32_bf16(a_h[mi], b_h[ni], acc[mi][ni], 0, 0, 0);
                    acc[mi][ni] = __builtin_amdgcn_mfma_f32_16x16x32_bf16(a_h[mi], b_l[ni], acc[mi][ni], 0, 0, 0);
                    acc[mi][ni] = __builtin_amdgcn_mfma_f32_16x16x32_bf16(a_l[mi], b_h[ni], acc[mi][ni], 0, 0, 0);
                }
        }
        #pragma unroll
        for (int mi = 0; mi < WM; ++mi)
            #pragma unroll
            for (int ni = 0; ni < WN; ++ni) {
                int col = ni * 16 + r;
                #pragma unroll
                for (int i = 0; i < 4; ++i)
                    l8[tLoc * 2 + ks][(mi * 16 + q * 4 + i) * 32 + col] = acc[mi][ni][i];
            }
        __syncthreads();
        for (int e = tid; e < 2 * 1536; e += 256) {
            int tl = (e >= 1536) ? 1 : 0;
            int idx = e - tl * 1536;
            int row = idx >> 5, col = idx & 31;
            int tg = blk * 2 + tl;
            int gm = (tg / ntN) * 48 + row, gn = (tg % ntN) * 32 + col;
            P.out[(size_t)gm * N + gn] = l8[tl * 2][idx] + l8[tl * 2 + 1][idx];
        }
    }
}

// ---------------------------------------------------------------------------
extern "C" void kernel_launch(void* const* d_in, const int* in_sizes, int n_in,
                              void* d_out, int out_size, void* d_ws, size_t ws_size,
                              hipStream_t stream)
{
    MegaParams P;
    P.hidden = (const float*)d_in[0];
    P.Win    = (const float*)d_in[1];
    P.Wxp    = (const float*)d_in[2];
    P.Wdt    = (const float*)d_in[3];
    P.bdt    = (const float*)d_in[4];
    P.AlogF  = (const float*)d_in[5];
    P.AlogB  = (const float*)d_in[6];
    P.Df     = (const float*)d_in[7];
    P.Db     = (const float*)d_in[8];
    P.Wglob  = (const float*)d_in[9];
    P.bglob  = (const float*)d_in[10];
    P.Wgate  = (const float*)d_in[11];
    P.bgate  = (const float*)d_in[12];
    P.Wout   = (const float*)d_in[13];
    P.out    = (float*)d_out;

    char* w = (char*)d_ws;
    P.xh     = (__bf16*)w; w += (size_t)BL * DINNER * 2;
    P.xl     = (__bf16*)w; w += (size_t)BL * DINNER * 2;
    P.z_silu = (float*)w;  w += (size_t)BL * DINNER * 4;
    P.dtBC   = (float*)w;  w += (size_t)BL * 48 * 4;
    P.dtb    = (float*)w;  w += (size_t)BL * DINNER * 4;
    P.yh     = (__bf16*)w; w += (size_t)BL * 2 * DINNER * 2;
    P.yl     = (__bf16*)w; w += (size_t)BL * 2 * DINNER * 2;
    P.partial= (float*)w;  w += (size_t)BB * NC * 1024 * 4;
    P.ymean  = (float*)w;  w += (size_t)BB * 1024 * 4;
    P.t1     = (float*)w;  w += (size_t)BB * 1024 * 4;
    P.gbuf   = (float*)w;  w += (size_t)BB * 1024 * 4;
    P.hh     = (__bf16*)w; w += (size_t)N_HID * 2;
    P.hl     = (__bf16*)w; w += (size_t)N_HID * 2;
    P.wih    = (__bf16*)w; w += (size_t)N_WIN * 2;
    P.wil    = (__bf16*)w; w += (size_t)N_WIN * 2;
    P.wxh    = (__bf16*)w; w += (size_t)N_WXP * 2;
    P.wxl    = (__bf16*)w; w += (size_t)N_WXP * 2;
    P.woh    = (__bf16*)w; w += (size_t)N_WOUT * 2;
    P.wol    = (__bf16*)w; w += (size_t)N_WOUT * 2;
    P.Pbuf   = (float*)w;  w += (size_t)BB * 2 * NC * DSTATE * DINNER * 4;  // 16.8 MB
    P.Qbuf   = (float*)w;  w += (size_t)BB * 2 * NC * DSTATE * DINNER * 4;  // 16.8 MB
    P.ctr    = (unsigned*)w; w += 64;

    init_ctrs<<<dim3(1), dim3(64), 0, stream>>>(P.ctr);
    mega<<<dim3(GRID), dim3(256), 0, stream>>>(P);
}

// Round 13
// 222.998 us; speedup vs baseline: 4.0019x; 4.0019x over previous
//
#include <hip/hip_runtime.h>
#include <hip/hip_bf16.h>

// Problem constants
#define BB 4
#define LL 900
#define DMODEL 256
#define DSTATE 16
#define DINNER 512
#define DTRANK 16
#define BL (BB*LL)          // 3600
#define NC 75               // scan chunks
#define LC 12               // steps per chunk; NC*LC == LL

typedef __bf16 bf16x8 __attribute__((ext_vector_type(8)));
typedef __bf16 bf16x4 __attribute__((ext_vector_type(4)));
typedef float f32x4 __attribute__((ext_vector_type(4)));

__device__ __forceinline__ float silu_f(float v) { return v / (1.f + __expf(-v)); }

// ---------------------------------------------------------------------------
// One-time bf16 conversion of GEMM operands (threshold is sized for bf16)
// ---------------------------------------------------------------------------
#define N_HID  (BL*DMODEL)             // 921600
#define N_WIN  (2*DINNER*DMODEL)       // 262144
#define N_WXP  (48*DINNER)             // 24576
#define N_WOUT (DMODEL*2*DINNER)       // 262144
#define N_TOT  (N_HID+N_WIN+N_WXP+N_WOUT)
__global__ void cvt_inputs(const float* __restrict__ hidden, const float* __restrict__ Win,
                           const float* __restrict__ Wxp, const float* __restrict__ Wout,
                           __bf16* __restrict__ hh, __bf16* __restrict__ wih,
                           __bf16* __restrict__ wxh, __bf16* __restrict__ woh)
{
    int idx = blockIdx.x * 256 + threadIdx.x;
    if (idx >= N_TOT) return;
    const float* src; __bf16* dst; int off;
    if (idx < N_HID)                        { src = hidden; dst = hh;  off = idx; }
    else if (idx < N_HID+N_WIN)             { src = Win;    dst = wih; off = idx - N_HID; }
    else if (idx < N_HID+N_WIN+N_WXP)       { src = Wxp;    dst = wxh; off = idx - N_HID - N_WIN; }
    else                                    { src = Wout;   dst = woh; off = idx - N_HID - N_WIN - N_WXP; }
    dst[off] = (__bf16)src[off];
}

// ---------------------------------------------------------------------------
// gemm1: xz = hidden @ W_in^T (M=3600,N=1024,K=256), bf16 MFMA, fused silu.
// Wave tile 48x32 (WM=3,WN=2); 2400 waves.
// cols <512 -> x bf16; cols >=512 -> z bf16 (silu'd).
// ---------------------------------------------------------------------------
__launch_bounds__(256)
__global__ void gemm_silu(const __bf16* __restrict__ A, const __bf16* __restrict__ B,
                          __bf16* __restrict__ xb, __bf16* __restrict__ zb)
{
    constexpr int WM = 3, WN = 2, K = 256, nk = K >> 5;
    constexpr int M = BL, N = 2 * DINNER;
    int wave = (blockIdx.x * 256 + threadIdx.x) >> 6;
    int ntN = N / (16 * WN);
    if (wave >= (M / (16 * WM)) * ntN) return;
    int tm = wave / ntN, tn = wave % ntN;
    int lane = threadIdx.x & 63, q = lane >> 4, r = lane & 15;

    const bf16x8* Ar[WM]; const bf16x8* Br[WN];
    #pragma unroll
    for (int mi = 0; mi < WM; ++mi)
        Ar[mi] = (const bf16x8*)(A + (size_t)(tm * 48 + mi * 16 + r) * K);
    #pragma unroll
    for (int ni = 0; ni < WN; ++ni)
        Br[ni] = (const bf16x8*)(B + (size_t)(tn * 32 + ni * 16 + r) * K);
    f32x4 acc[WM][WN];
    #pragma unroll
    for (int mi = 0; mi < WM; ++mi)
        #pragma unroll
        for (int ni = 0; ni < WN; ++ni) acc[mi][ni] = (f32x4){0.f,0.f,0.f,0.f};

    #pragma unroll
    for (int kk = 0; kk < nk; ++kk) {
        int idx = kk * 4 + q;
        bf16x8 av[WM], bv[WN];
        #pragma unroll
        for (int mi = 0; mi < WM; ++mi) av[mi] = Ar[mi][idx];
        #pragma unroll
        for (int ni = 0; ni < WN; ++ni) bv[ni] = Br[ni][idx];
        #pragma unroll
        for (int mi = 0; mi < WM; ++mi)
            #pragma unroll
            for (int ni = 0; ni < WN; ++ni)
                acc[mi][ni] = __builtin_amdgcn_mfma_f32_16x16x32_bf16(av[mi], bv[ni], acc[mi][ni], 0, 0, 0);
    }
    #pragma unroll
    for (int mi = 0; mi < WM; ++mi)
        #pragma unroll
        for (int ni = 0; ni < WN; ++ni) {
            int col = tn * 32 + ni * 16 + r;
            #pragma unroll
            for (int i = 0; i < 4; ++i) {
                int row = tm * 48 + mi * 16 + q * 4 + i;
                float s = silu_f(acc[mi][ni][i]);
                if (col < DINNER) xb[(size_t)row * DINNER + col] = (__bf16)s;
                else              zb[(size_t)row * DINNER + (col - DINNER)] = (__bf16)s;
            }
        }
}

// ---------------------------------------------------------------------------
// gemm2 + dt fused: x_dbl = x @ W_xproj^T (M=3600,N=48,K=512), KS=4 K-split
// combined in LDS, then dt = softplus(dt_r @ Wdt^T + bdt) for the 16 rows.
// ---------------------------------------------------------------------------
__launch_bounds__(256)
__global__ void gemm2_dt(const __bf16* __restrict__ A, const __bf16* __restrict__ B,
                         const float* __restrict__ Wdt, const float* __restrict__ bdt,
                         float* __restrict__ dtBC, float* __restrict__ dtb)
{
    constexpr int WN = 3, K = 512, KSL = 128, nk = KSL >> 5;   // 4 chunks
    __shared__ float lds[4][16 * 48];
    int tm = blockIdx.x;                       // 225 tiles (16 rows each)
    int wv = threadIdx.x >> 6, kOff = wv * KSL;
    int lane = threadIdx.x & 63, q = lane >> 4, r = lane & 15;

    const bf16x8* Ar = (const bf16x8*)(A + (size_t)(tm * 16 + r) * K + kOff);
    const bf16x8* Br[WN];
    #pragma unroll
    for (int ni = 0; ni < WN; ++ni)
        Br[ni] = (const bf16x8*)(B + (size_t)(ni * 16 + r) * K + kOff);
    f32x4 acc[WN];
    #pragma unroll
    for (int ni = 0; ni < WN; ++ni) acc[ni] = (f32x4){0.f,0.f,0.f,0.f};

    #pragma unroll
    for (int kk = 0; kk < nk; ++kk) {
        int idx = kk * 4 + q;
        bf16x8 av = Ar[idx];
        #pragma unroll
        for (int ni = 0; ni < WN; ++ni)
            acc[ni] = __builtin_amdgcn_mfma_f32_16x16x32_bf16(av, Br[ni][idx], acc[ni], 0, 0, 0);
    }
    #pragma unroll
    for (int ni = 0; ni < WN; ++ni) {
        int col = ni * 16 + r;
        #pragma unroll
        for (int i = 0; i < 4; ++i)
            lds[wv][(q * 4 + i) * 48 + col] = acc[ni][i];
    }
    __syncthreads();
    for (int e = threadIdx.x; e < 16 * 48; e += 256) {
        float s = lds[0][e] + lds[1][e] + lds[2][e] + lds[3][e];
        lds[0][e] = s;
        int row = e / 48, col = e % 48;
        dtBC[(size_t)(tm * 16 + row) * 48 + col] = s;
    }
    __syncthreads();
    for (int it = 0; it < 32; ++it) {
        int e = threadIdx.x + it * 256;        // 8192
        int row = e >> 9, d = e & 511;
        const float* wr = Wdt + (size_t)d * DTRANK;
        float s = bdt[d];
        #pragma unroll
        for (int k = 0; k < DTRANK; ++k) s = fmaf(lds[0][row * 48 + k], wr[k], s);
        dtb[(size_t)(tm * 16 + row) * DINNER + d] = (s > 15.f) ? s : __logf(1.f + __expf(s));
    }
}

// ---------------------------------------------------------------------------
// Scan pass 1: per-chunk zero-init run -> Q (end state), P = exp2(a2*Σdt).
// Layout P/Q: [b][dir][c][n][d] (d fastest).
// ---------------------------------------------------------------------------
__global__ void scan_pass1(const float* __restrict__ dtb,
                           const __bf16* __restrict__ xb,
                           const float* __restrict__ dtBC,
                           const float* __restrict__ AlogF, const float* __restrict__ AlogB,
                           float* __restrict__ Pbuf, float* __restrict__ Qbuf)
{
    int b = blockIdx.z, dir = blockIdx.y;
    int c = blockIdx.x >> 2, dgrp = blockIdx.x & 3;
    int d = dgrp * 128 + threadIdx.x;
    const float* Alog = dir ? AlogB : AlogF;
    float a2[DSTATE];
    #pragma unroll
    for (int n = 0; n < DSTATE; ++n) a2[n] = -__expf(Alog[d * DSTATE + n]) * 1.44269504f;
    float h[DSTATE];
    #pragma unroll
    for (int n = 0; n < DSTATE; ++n) h[n] = 0.f;
    float sdt = 0.f;

    #pragma unroll 4
    for (int il = 0; il < LC; ++il) {
        int i = c * LC + il;
        int l = dir ? (LL - 1 - i) : i;
        size_t base = (size_t)b * LL + l;
        float dtv = dtb[base * DINNER + d];
        float u = (float)xb[base * DINNER + d];
        float du = dtv * u;
        const f32x4* Bp = (const f32x4*)(dtBC + base * 48 + DTRANK);
        f32x4 Bq[4];
        #pragma unroll
        for (int j = 0; j < 4; ++j) Bq[j] = Bp[j];
        sdt += dtv;
        #pragma unroll
        for (int n = 0; n < DSTATE; ++n)
            h[n] = fmaf(exp2f(dtv * a2[n]), h[n], du * Bq[n >> 2][n & 3]);
    }
    size_t o = (((size_t)(b * 2 + dir) * NC + c) * DSTATE) * DINNER + d;
    #pragma unroll
    for (int n = 0; n < DSTATE; ++n) {
        Pbuf[o + (size_t)n * DINNER] = exp2f(sdt * a2[n]);
        Qbuf[o + (size_t)n * DINNER] = h[n];
    }
}

// Pass 2: stitch in place (H0 overwrites Pbuf), batched 15-wide prefetch.
__global__ void scan_stitch(float* __restrict__ Pbuf, const float* __restrict__ Qbuf)
{
    int idx = blockIdx.x * 256 + threadIdx.x;   // 65536
    int bd = idx >> 13;
    int rem = idx & 8191;
    size_t base = (size_t)bd * NC * 8192 + rem;
    float H = 0.f;
    for (int cb = 0; cb < NC; cb += 15) {
        float Pv[15], Qv[15];
        #pragma unroll
        for (int j = 0; j < 15; ++j) {
            size_t o = base + (size_t)(cb + j) * 8192;
            Pv[j] = Pbuf[o];
            Qv[j] = Qbuf[o];
        }
        #pragma unroll
        for (int j = 0; j < 15; ++j) {
            Pbuf[base + (size_t)(cb + j) * 8192] = H;
            H = fmaf(Pv[j], H, Qv[j]);
        }
    }
}

// Pass 3: re-run chunk from true initial state (in Pbuf); emit y bf16 + partials.
// zb is ALREADY silu'd.
__global__ void scan_pass3(const float* __restrict__ dtb,
                           const __bf16* __restrict__ xb,
                           const float* __restrict__ dtBC,
                           const float* __restrict__ AlogF, const float* __restrict__ AlogB,
                           const float* __restrict__ Df, const float* __restrict__ Db,
                           const __bf16* __restrict__ zb,
                           const float* __restrict__ H0buf,
                           __bf16* __restrict__ yb,        // [B,L,1024]
                           float* __restrict__ partial)    // [B,NC,1024]
{
    int b = blockIdx.z, dir = blockIdx.y;
    int c = blockIdx.x >> 2, dgrp = blockIdx.x & 3;
    int d = dgrp * 128 + threadIdx.x;
    const float* Alog = dir ? AlogB : AlogF;
    float a2[DSTATE];
    #pragma unroll
    for (int n = 0; n < DSTATE; ++n) a2[n] = -__expf(Alog[d * DSTATE + n]) * 1.44269504f;
    float Dd = dir ? Db[d] : Df[d];
    size_t o = (((size_t)(b * 2 + dir) * NC + c) * DSTATE) * DINNER + d;
    float h[DSTATE];
    #pragma unroll
    for (int n = 0; n < DSTATE; ++n) h[n] = H0buf[o + (size_t)n * DINNER];
    float ysum = 0.f;

    #pragma unroll 4
    for (int il = 0; il < LC; ++il) {
        int i = c * LC + il;
        int l = dir ? (LL - 1 - i) : i;
        size_t base = (size_t)b * LL + l;
        float dtv = dtb[base * DINNER + d];
        float u = (float)xb[base * DINNER + d];
        float du = dtv * u;
        const f32x4* Bp = (const f32x4*)(dtBC + base * 48 + DTRANK);
        f32x4 Bq[4], Cq[4];
        #pragma unroll
        for (int j = 0; j < 4; ++j) Bq[j] = Bp[j];
        #pragma unroll
        for (int j = 0; j < 4; ++j) Cq[j] = Bp[4 + j];
        float p = 0.f;
        #pragma unroll
        for (int n = 0; n < DSTATE; ++n) {
            h[n] = fmaf(exp2f(dtv * a2[n]), h[n], du * Bq[n >> 2][n & 3]);
            p = fmaf(h[n], Cq[n >> 2][n & 3], p);
        }
        float zg = (float)zb[base * DINNER + d];
        float yv = (p + Dd * u) * zg;
        size_t yo = base * (2 * DINNER) + dir * DINNER + d;
        yb[yo] = (__bf16)yv;
        ysum += yv;
    }
    partial[((size_t)b * NC + c) * 1024 + dir * DINNER + d] = ysum;
}

// mean over chunks -> ymean[b,1024]
__global__ void mean2(const float* __restrict__ partial, float* __restrict__ ymean)
{
    int i = blockIdx.x * 256 + threadIdx.x;   // 4096
    int b = i >> 10, ch = i & 1023;
    float s = 0.f;
    #pragma unroll 5
    for (int c = 0; c < NC; ++c) s += partial[((size_t)b * NC + c) * 1024 + ch];
    ymean[i] = s / (float)LL;
}

// gemv: one wave per (b,j); 4096 waves.
template<int SIG>
__global__ void gemv1024(const float* __restrict__ vin,
                         const float* __restrict__ W,
                         const float* __restrict__ bias,
                         float* __restrict__ vout)
{
    int wv = (blockIdx.x * blockDim.x + threadIdx.x) >> 6;
    int b = wv >> 10, j = wv & 1023;
    int lane = threadIdx.x & 63;
    const float* wr = W + (size_t)j * 1024;
    const float* vr = vin + (size_t)b * 1024;
    float s = 0.f;
    for (int k = lane; k < 1024; k += 64) s = fmaf(vr[k], wr[k], s);
    #pragma unroll
    for (int o = 32; o; o >>= 1) s += __shfl_xor(s, o);
    if (lane == 0) {
        s += bias[j];
        vout[wv] = SIG ? (1.f / (1.f + __expf(-s))) : s;
    }
}

// y *= g[b,ch] (bf16 in place, 8 elems/thread)
__global__ void scale_y(__bf16* __restrict__ yb, const float* __restrict__ g)
{
    int idx = blockIdx.x * 256 + threadIdx.x;   // BL*1024/8 = 460800
    int e = idx * 8;
    int ch = e & 1023;
    int b = (e >> 10) / LL;
    bf16x8 v = reinterpret_cast<bf16x8*>(yb)[idx];
    const f32x4* gp = (const f32x4*)(g + b * 1024 + ch);
    f32x4 g0 = gp[0], g1 = gp[1];
    #pragma unroll
    for (int j = 0; j < 4; ++j) v[j] = (__bf16)((float)v[j] * g0[j]);
    #pragma unroll
    for (int j = 0; j < 4; ++j) v[4 + j] = (__bf16)((float)v[4 + j] * g1[j]);
    reinterpret_cast<bf16x8*>(yb)[idx] = v;
}

// ---------------------------------------------------------------------------
// gemm8: out = y @ W_out^T (M=3600,N=256,K=1024), KS=2 combined in LDS.
// ---------------------------------------------------------------------------
__launch_bounds__(256)
__global__ void gemm8_comb(const __bf16* __restrict__ A, const __bf16* __restrict__ B,
                           float* __restrict__ out)
{
    constexpr int WM = 3, WN = 2, K = 1024, KSL = 512, nk = KSL >> 5;  // 16 chunks
    constexpr int N = DMODEL, ntN = N / (16 * WN);                      // 8
    __shared__ float lds[2][2][48 * 32];
    int wv = threadIdx.x >> 6;
    int tLoc = wv >> 1, ks = wv & 1;
    int tIdx = blockIdx.x * 2 + tLoc;          // 600 tiles
    int tm = tIdx / ntN, tn = tIdx % ntN;
    int kOff = ks * KSL;
    int lane = threadIdx.x & 63, q = lane >> 4, r = lane & 15;

    const bf16x8* Ar[WM]; const bf16x8* Br[WN];
    #pragma unroll
    for (int mi = 0; mi < WM; ++mi)
        Ar[mi] = (const bf16x8*)(A + (size_t)(tm * 48 + mi * 16 + r) * K + kOff);
    #pragma unroll
    for (int ni = 0; ni < WN; ++ni)
        Br[ni] = (const bf16x8*)(B + (size_t)(tn * 32 + ni * 16 + r) * K + kOff);
    f32x4 acc[WM][WN];
    #pragma unroll
    for (int mi = 0; mi < WM; ++mi)
        #pragma unroll
        for (int ni = 0; ni < WN; ++ni) acc[mi][ni] = (f32x4){0.f,0.f,0.f,0.f};

    #pragma unroll
    for (int kk = 0; kk < nk; ++kk) {
        int idx = kk * 4 + q;
        bf16x8 av[WM], bv[WN];
        #pragma unroll
        for (int mi = 0; mi < WM; ++mi) av[mi] = Ar[mi][idx];
        #pragma unroll
        for (int ni = 0; ni < WN; ++ni) bv[ni] = Br[ni][idx];
        #pragma unroll
        for (int mi = 0; mi < WM; ++mi)
            #pragma unroll
            for (int ni = 0; ni < WN; ++ni)
                acc[mi][ni] = __builtin_amdgcn_mfma_f32_16x16x32_bf16(av[mi], bv[ni], acc[mi][ni], 0, 0, 0);
    }
    #pragma unroll
    for (int mi = 0; mi < WM; ++mi)
        #pragma unroll
        for (int ni = 0; ni < WN; ++ni) {
            int col = ni * 16 + r;
            #pragma unroll
            for (int i = 0; i < 4; ++i)
                lds[tLoc][ks][(mi * 16 + q * 4 + i) * 32 + col] = acc[mi][ni][i];
        }
    __syncthreads();
    // packed 2*1536 range; tl = e/1536 (round-9 bug fixed in r10)
    for (int e = threadIdx.x; e < 2 * 1536; e += 256) {
        int tl = (e >= 1536) ? 1 : 0;
        int idx = e - tl * 1536;
        int row = idx >> 5, col = idx & 31;
        int tg = blockIdx.x * 2 + tl;
        int gm = (tg / ntN) * 48 + row, gn = (tg % ntN) * 32 + col;
        out[(size_t)gm * N + gn] = lds[tl][0][idx] + lds[tl][1][idx];
    }
}

// ---------------------------------------------------------------------------
extern "C" void kernel_launch(void* const* d_in, const int* in_sizes, int n_in,
                              void* d_out, int out_size, void* d_ws, size_t ws_size,
                              hipStream_t stream)
{
    const float* hidden  = (const float*)d_in[0];
    const float* W_in    = (const float*)d_in[1];
    const float* W_xproj = (const float*)d_in[2];
    const float* W_dt    = (const float*)d_in[3];
    const float* b_dt    = (const float*)d_in[4];
    const float* A_log_f = (const float*)d_in[5];
    const float* A_log_b = (const float*)d_in[6];
    const float* D_f     = (const float*)d_in[7];
    const float* D_b     = (const float*)d_in[8];
    const float* W_glob  = (const float*)d_in[9];
    const float* b_glob  = (const float*)d_in[10];
    const float* W_gate  = (const float*)d_in[11];
    const float* b_gate  = (const float*)d_in[12];
    const float* W_out   = (const float*)d_in[13];
    float* out = (float*)d_out;

    // workspace (~66 MB)
    char* w = (char*)d_ws;
    __bf16* xb    = (__bf16*)w; w += (size_t)BL * DINNER * 2;            // 3.69 MB
    __bf16* zb    = (__bf16*)w; w += (size_t)BL * DINNER * 2;            // 3.69 MB
    float* dtBC   = (float*)w;  w += (size_t)BL * 48 * 4;
    float* dtb    = (float*)w;  w += (size_t)BL * DINNER * 4;            // 7.37 MB
    __bf16* yb    = (__bf16*)w; w += (size_t)BL * 2 * DINNER * 2;        // 7.37 MB
    float* partial= (float*)w;  w += (size_t)BB * NC * 1024 * 4;
    float* ymean  = (float*)w;  w += (size_t)BB * 1024 * 4;
    float* t1     = (float*)w;  w += (size_t)BB * 1024 * 4;
    float* gbuf   = (float*)w;  w += (size_t)BB * 1024 * 4;
    __bf16* hh    = (__bf16*)w; w += (size_t)N_HID * 2;
    __bf16* wih   = (__bf16*)w; w += (size_t)N_WIN * 2;
    __bf16* wxh   = (__bf16*)w; w += (size_t)N_WXP * 2;
    __bf16* woh   = (__bf16*)w; w += (size_t)N_WOUT * 2;
    float* Pbuf   = (float*)w;  w += (size_t)BB * 2 * NC * DSTATE * DINNER * 4;  // 19.7 MB
    float* Qbuf   = (float*)w;  w += (size_t)BB * 2 * NC * DSTATE * DINNER * 4;  // 19.7 MB

    // 0) bf16 conversion of hidden + weights
    cvt_inputs<<<dim3((N_TOT + 255) / 256), dim3(256), 0, stream>>>(
        hidden, W_in, W_xproj, W_out, hh, wih, wxh, woh);
    // 1) xz = hidden @ W_in^T, fused silu (2400 waves)
    gemm_silu<<<dim3(600), dim3(256), 0, stream>>>(hh, wih, xb, zb);
    // 2) x_dbl + dt, fused (225 blocks)
    gemm2_dt<<<dim3(225), dim3(256), 0, stream>>>(xb, wxh, W_dt, b_dt, dtBC, dtb);
    // 3) chunked scan (4800 waves/pass)
    scan_pass1<<<dim3(NC * 4, 2, BB), dim3(128), 0, stream>>>(
        dtb, xb, dtBC, A_log_f, A_log_b, Pbuf, Qbuf);
    scan_stitch<<<dim3(256), dim3(256), 0, stream>>>(Pbuf, Qbuf);
    scan_pass3<<<dim3(NC * 4, 2, BB), dim3(128), 0, stream>>>(
        dtb, xb, dtBC, A_log_f, A_log_b, D_f, D_b, zb, Pbuf, yb, partial);
    // 4) mean
    mean2<<<dim3(16), dim3(256), 0, stream>>>(partial, ymean);
    // 5) gating
    gemv1024<0><<<dim3(1024), dim3(256), 0, stream>>>(ymean, W_glob, b_glob, t1);
    gemv1024<1><<<dim3(1024), dim3(256), 0, stream>>>(t1, W_gate, b_gate, gbuf);
    // 6) y *= g (bf16 in place)
    scale_y<<<dim3(BL * 1024 / 8 / 256), dim3(256), 0, stream>>>(yb, gbuf);
    // 7) out = y @ W_out^T, KS=2 LDS-combined (300 blocks)
    gemm8_comb<<<dim3(300), dim3(256), 0, stream>>>(yb, woh, out);
}

// Round 14
// 219.652 us; speedup vs baseline: 4.0629x; 1.0152x over previous
//
#include <hip/hip_runtime.h>
#include <hip/hip_bf16.h>

// Problem constants
#define BB 4
#define LL 900
#define DMODEL 256
#define DSTATE 16
#define DINNER 512
#define DTRANK 16
#define BL (BB*LL)          // 3600
#define NC 75               // scan chunks
#define LC 12               // steps per chunk; NC*LC == LL

typedef __bf16 bf16x8 __attribute__((ext_vector_type(8)));
typedef __bf16 bf16x4 __attribute__((ext_vector_type(4)));
typedef float f32x4 __attribute__((ext_vector_type(4)));

__device__ __forceinline__ float silu_f(float v) { return v / (1.f + __expf(-v)); }

// ---------------------------------------------------------------------------
// One-time bf16 conversion of GEMM/GEMV operands
// ---------------------------------------------------------------------------
#define N_HID  (BL*DMODEL)             // 921600
#define N_WIN  (2*DINNER*DMODEL)       // 262144
#define N_WXP  (48*DINNER)             // 24576
#define N_WOUT (DMODEL*2*DINNER)       // 262144
#define N_WG   (2*DINNER*2*DINNER)     // 1048576
#define N_TOT  (N_HID+N_WIN+N_WXP+N_WOUT+2*N_WG)
__global__ void cvt_inputs(const float* __restrict__ hidden, const float* __restrict__ Win,
                           const float* __restrict__ Wxp, const float* __restrict__ Wout,
                           const float* __restrict__ Wglob, const float* __restrict__ Wgate,
                           __bf16* __restrict__ hh, __bf16* __restrict__ wih,
                           __bf16* __restrict__ wxh, __bf16* __restrict__ woh,
                           __bf16* __restrict__ wgb, __bf16* __restrict__ wtb)
{
    int idx = blockIdx.x * 256 + threadIdx.x;
    if (idx >= N_TOT) return;
    const float* src; __bf16* dst; int off;
    if (idx < N_HID)                              { src = hidden; dst = hh;  off = idx; }
    else if (idx < N_HID+N_WIN)                   { src = Win;    dst = wih; off = idx - N_HID; }
    else if (idx < N_HID+N_WIN+N_WXP)             { src = Wxp;    dst = wxh; off = idx - N_HID - N_WIN; }
    else if (idx < N_HID+N_WIN+N_WXP+N_WOUT)      { src = Wout;   dst = woh; off = idx - N_HID - N_WIN - N_WXP; }
    else if (idx < N_HID+N_WIN+N_WXP+N_WOUT+N_WG) { src = Wglob;  dst = wgb; off = idx - N_HID - N_WIN - N_WXP - N_WOUT; }
    else                                          { src = Wgate;  dst = wtb; off = idx - N_HID - N_WIN - N_WXP - N_WOUT - N_WG; }
    dst[off] = (__bf16)src[off];
}

// ---------------------------------------------------------------------------
// gemm1: xz = hidden @ W_in^T (M=3600,N=1024,K=256), bf16 MFMA, fused silu.
// Wave tile 48x32 (WM=3,WN=2); 2400 waves.
// ---------------------------------------------------------------------------
__launch_bounds__(256)
__global__ void gemm_silu(const __bf16* __restrict__ A, const __bf16* __restrict__ B,
                          __bf16* __restrict__ xb, __bf16* __restrict__ zb)
{
    constexpr int WM = 3, WN = 2, K = 256, nk = K >> 5;
    constexpr int M = BL, N = 2 * DINNER;
    int wave = (blockIdx.x * 256 + threadIdx.x) >> 6;
    int ntN = N / (16 * WN);
    if (wave >= (M / (16 * WM)) * ntN) return;
    int tm = wave / ntN, tn = wave % ntN;
    int lane = threadIdx.x & 63, q = lane >> 4, r = lane & 15;

    const bf16x8* Ar[WM]; const bf16x8* Br[WN];
    #pragma unroll
    for (int mi = 0; mi < WM; ++mi)
        Ar[mi] = (const bf16x8*)(A + (size_t)(tm * 48 + mi * 16 + r) * K);
    #pragma unroll
    for (int ni = 0; ni < WN; ++ni)
        Br[ni] = (const bf16x8*)(B + (size_t)(tn * 32 + ni * 16 + r) * K);
    f32x4 acc[WM][WN];
    #pragma unroll
    for (int mi = 0; mi < WM; ++mi)
        #pragma unroll
        for (int ni = 0; ni < WN; ++ni) acc[mi][ni] = (f32x4){0.f,0.f,0.f,0.f};

    #pragma unroll
    for (int kk = 0; kk < nk; ++kk) {
        int idx = kk * 4 + q;
        bf16x8 av[WM], bv[WN];
        #pragma unroll
        for (int mi = 0; mi < WM; ++mi) av[mi] = Ar[mi][idx];
        #pragma unroll
        for (int ni = 0; ni < WN; ++ni) bv[ni] = Br[ni][idx];
        #pragma unroll
        for (int mi = 0; mi < WM; ++mi)
            #pragma unroll
            for (int ni = 0; ni < WN; ++ni)
                acc[mi][ni] = __builtin_amdgcn_mfma_f32_16x16x32_bf16(av[mi], bv[ni], acc[mi][ni], 0, 0, 0);
    }
    #pragma unroll
    for (int mi = 0; mi < WM; ++mi)
        #pragma unroll
        for (int ni = 0; ni < WN; ++ni) {
            int col = tn * 32 + ni * 16 + r;
            #pragma unroll
            for (int i = 0; i < 4; ++i) {
                int row = tm * 48 + mi * 16 + q * 4 + i;
                float s = silu_f(acc[mi][ni][i]);
                if (col < DINNER) xb[(size_t)row * DINNER + col] = (__bf16)s;
                else              zb[(size_t)row * DINNER + (col - DINNER)] = (__bf16)s;
            }
        }
}

// ---------------------------------------------------------------------------
// gemm2 + dt fused: x_dbl = x @ W_xproj^T (M=3600,N=48,K=512), KS=4 K-split
// combined in LDS, then dt = softplus(...) -> dtb (bf16)
// ---------------------------------------------------------------------------
__launch_bounds__(256)
__global__ void gemm2_dt(const __bf16* __restrict__ A, const __bf16* __restrict__ B,
                         const float* __restrict__ Wdt, const float* __restrict__ bdt,
                         float* __restrict__ dtBC, __bf16* __restrict__ dtb)
{
    constexpr int WN = 3, K = 512, KSL = 128, nk = KSL >> 5;   // 4 chunks
    __shared__ float lds[4][16 * 48];
    int tm = blockIdx.x;                       // 225 tiles (16 rows each)
    int wv = threadIdx.x >> 6, kOff = wv * KSL;
    int lane = threadIdx.x & 63, q = lane >> 4, r = lane & 15;

    const bf16x8* Ar = (const bf16x8*)(A + (size_t)(tm * 16 + r) * K + kOff);
    const bf16x8* Br[WN];
    #pragma unroll
    for (int ni = 0; ni < WN; ++ni)
        Br[ni] = (const bf16x8*)(B + (size_t)(ni * 16 + r) * K + kOff);
    f32x4 acc[WN];
    #pragma unroll
    for (int ni = 0; ni < WN; ++ni) acc[ni] = (f32x4){0.f,0.f,0.f,0.f};

    #pragma unroll
    for (int kk = 0; kk < nk; ++kk) {
        int idx = kk * 4 + q;
        bf16x8 av = Ar[idx];
        #pragma unroll
        for (int ni = 0; ni < WN; ++ni)
            acc[ni] = __builtin_amdgcn_mfma_f32_16x16x32_bf16(av, Br[ni][idx], acc[ni], 0, 0, 0);
    }
    #pragma unroll
    for (int ni = 0; ni < WN; ++ni) {
        int col = ni * 16 + r;
        #pragma unroll
        for (int i = 0; i < 4; ++i)
            lds[wv][(q * 4 + i) * 48 + col] = acc[ni][i];
    }
    __syncthreads();
    for (int e = threadIdx.x; e < 16 * 48; e += 256) {
        float s = lds[0][e] + lds[1][e] + lds[2][e] + lds[3][e];
        lds[0][e] = s;
        int row = e / 48, col = e % 48;
        dtBC[(size_t)(tm * 16 + row) * 48 + col] = s;
    }
    __syncthreads();
    for (int it = 0; it < 32; ++it) {
        int e = threadIdx.x + it * 256;        // 8192
        int row = e >> 9, d = e & 511;
        const float* wr = Wdt + (size_t)d * DTRANK;
        float s = bdt[d];
        #pragma unroll
        for (int k = 0; k < DTRANK; ++k) s = fmaf(lds[0][row * 48 + k], wr[k], s);
        float dtv = (s > 15.f) ? s : __logf(1.f + __expf(s));
        dtb[(size_t)(tm * 16 + row) * DINNER + d] = (__bf16)dtv;
    }
}

// ---------------------------------------------------------------------------
// Scan pass 1: per-chunk zero-init run -> Q (end state, bf16), sdt (scalar).
// Q layout: [bd][c][n][d] (d fastest). sdt: [bd][c][d].
// ---------------------------------------------------------------------------
__global__ void scan_pass1(const __bf16* __restrict__ dtb,
                           const __bf16* __restrict__ xb,
                           const float* __restrict__ dtBC,
                           const float* __restrict__ AlogF, const float* __restrict__ AlogB,
                           float* __restrict__ sdtBuf, __bf16* __restrict__ Qbuf)
{
    int b = blockIdx.z, dir = blockIdx.y;
    int c = blockIdx.x >> 2, dgrp = blockIdx.x & 3;
    int d = dgrp * 128 + threadIdx.x;
    const float* Alog = dir ? AlogB : AlogF;
    float a2[DSTATE];
    #pragma unroll
    for (int n = 0; n < DSTATE; ++n) a2[n] = -__expf(Alog[d * DSTATE + n]) * 1.44269504f;
    float h[DSTATE];
    #pragma unroll
    for (int n = 0; n < DSTATE; ++n) h[n] = 0.f;
    float sdt = 0.f;

    #pragma unroll 4
    for (int il = 0; il < LC; ++il) {
        int i = c * LC + il;
        int l = dir ? (LL - 1 - i) : i;
        size_t base = (size_t)b * LL + l;
        float dtv = (float)dtb[base * DINNER + d];
        float u = (float)xb[base * DINNER + d];
        float du = dtv * u;
        const f32x4* Bp = (const f32x4*)(dtBC + base * 48 + DTRANK);
        f32x4 Bq[4];
        #pragma unroll
        for (int j = 0; j < 4; ++j) Bq[j] = Bp[j];
        sdt += dtv;
        #pragma unroll
        for (int n = 0; n < DSTATE; ++n)
            h[n] = fmaf(exp2f(dtv * a2[n]), h[n], du * Bq[n >> 2][n & 3]);
    }
    int bd = b * 2 + dir;
    sdtBuf[((size_t)bd * NC + c) * DINNER + d] = sdt;
    size_t o = (((size_t)bd * NC + c) * DSTATE) * DINNER + d;
    #pragma unroll
    for (int n = 0; n < DSTATE; ++n)
        Qbuf[o + (size_t)n * DINNER] = (__bf16)h[n];
}

// Pass 2: stitch in place on Qbuf (H0 overwrites Q); P recomputed from sdt.
__global__ void scan_stitch(const float* __restrict__ sdtBuf,
                            const float* __restrict__ AlogF, const float* __restrict__ AlogB,
                            __bf16* __restrict__ Qbuf)
{
    int idx = blockIdx.x * 256 + threadIdx.x;   // 65536
    int bd = idx >> 13;
    int rem = idx & 8191;           // n*512 + d
    int n = rem >> 9, d = rem & 511;
    const float* Alog = (bd & 1) ? AlogB : AlogF;
    float a2 = -__expf(Alog[d * DSTATE + n]) * 1.44269504f;
    size_t qbase = (size_t)bd * NC * 8192 + rem;
    size_t sbase = (size_t)bd * NC * DINNER + d;
    float H = 0.f;
    for (int cb = 0; cb < NC; cb += 15) {
        float Qv[15], Sv[15];
        #pragma unroll
        for (int j = 0; j < 15; ++j) {
            Qv[j] = (float)Qbuf[qbase + (size_t)(cb + j) * 8192];
            Sv[j] = sdtBuf[sbase + (size_t)(cb + j) * DINNER];
        }
        #pragma unroll
        for (int j = 0; j < 15; ++j) {
            Qbuf[qbase + (size_t)(cb + j) * 8192] = (__bf16)H;   // H0 for chunk
            H = fmaf(exp2f(Sv[j] * a2), H, Qv[j]);
        }
    }
}

// Pass 3: re-run chunk from true initial state (bf16 H0 in Qbuf); emit y + partials.
__global__ void scan_pass3(const __bf16* __restrict__ dtb,
                           const __bf16* __restrict__ xb,
                           const float* __restrict__ dtBC,
                           const float* __restrict__ AlogF, const float* __restrict__ AlogB,
                           const float* __restrict__ Df, const float* __restrict__ Db,
                           const __bf16* __restrict__ zb,
                           const __bf16* __restrict__ H0buf,
                           __bf16* __restrict__ yb,        // [B,L,1024]
                           float* __restrict__ partial)    // [B,NC,1024]
{
    int b = blockIdx.z, dir = blockIdx.y;
    int c = blockIdx.x >> 2, dgrp = blockIdx.x & 3;
    int d = dgrp * 128 + threadIdx.x;
    const float* Alog = dir ? AlogB : AlogF;
    float a2[DSTATE];
    #pragma unroll
    for (int n = 0; n < DSTATE; ++n) a2[n] = -__expf(Alog[d * DSTATE + n]) * 1.44269504f;
    float Dd = dir ? Db[d] : Df[d];
    size_t o = (((size_t)(b * 2 + dir) * NC + c) * DSTATE) * DINNER + d;
    float h[DSTATE];
    #pragma unroll
    for (int n = 0; n < DSTATE; ++n) h[n] = (float)H0buf[o + (size_t)n * DINNER];
    float ysum = 0.f;

    #pragma unroll 4
    for (int il = 0; il < LC; ++il) {
        int i = c * LC + il;
        int l = dir ? (LL - 1 - i) : i;
        size_t base = (size_t)b * LL + l;
        float dtv = (float)dtb[base * DINNER + d];
        float u = (float)xb[base * DINNER + d];
        float du = dtv * u;
        const f32x4* Bp = (const f32x4*)(dtBC + base * 48 + DTRANK);
        f32x4 Bq[4], Cq[4];
        #pragma unroll
        for (int j = 0; j < 4; ++j) Bq[j] = Bp[j];
        #pragma unroll
        for (int j = 0; j < 4; ++j) Cq[j] = Bp[4 + j];
        float p = 0.f;
        #pragma unroll
        for (int n = 0; n < DSTATE; ++n) {
            h[n] = fmaf(exp2f(dtv * a2[n]), h[n], du * Bq[n >> 2][n & 3]);
            p = fmaf(h[n], Cq[n >> 2][n & 3], p);
        }
        float zg = (float)zb[base * DINNER + d];
        float yv = (p + Dd * u) * zg;
        size_t yo = base * (2 * DINNER) + dir * DINNER + d;
        yb[yo] = (__bf16)yv;
        ysum += yv;
    }
    partial[((size_t)b * NC + c) * 1024 + dir * DINNER + d] = ysum;
}

// mean over chunks -> ymean[b,1024]
__global__ void mean2(const float* __restrict__ partial, float* __restrict__ ymean)
{
    int i = blockIdx.x * 256 + threadIdx.x;   // 4096
    int b = i >> 10, ch = i & 1023;
    float s = 0.f;
    #pragma unroll 5
    for (int c = 0; c < NC; ++c) s += partial[((size_t)b * NC + c) * 1024 + ch];
    ymean[i] = s / (float)LL;
}

// gemv: one wave per (b,j); 4096 waves; bf16 weights.
template<int SIG>
__global__ void gemv1024(const float* __restrict__ vin,
                         const __bf16* __restrict__ W,
                         const float* __restrict__ bias,
                         float* __restrict__ vout)
{
    int wv = (blockIdx.x * blockDim.x + threadIdx.x) >> 6;
    int b = wv >> 10, j = wv & 1023;
    int lane = threadIdx.x & 63;
    const __bf16* wr = W + (size_t)j * 1024;
    const float* vr = vin + (size_t)b * 1024;
    float s = 0.f;
    for (int k = lane; k < 1024; k += 64) s = fmaf(vr[k], (float)wr[k], s);
    #pragma unroll
    for (int o = 32; o; o >>= 1) s += __shfl_xor(s, o);
    if (lane == 0) {
        s += bias[j];
        vout[wv] = SIG ? (1.f / (1.f + __expf(-s))) : s;
    }
}

// y *= g[b,ch] (bf16 in place, 8 elems/thread)
__global__ void scale_y(__bf16* __restrict__ yb, const float* __restrict__ g)
{
    int idx = blockIdx.x * 256 + threadIdx.x;   // BL*1024/8 = 460800
    int e = idx * 8;
    int ch = e & 1023;
    int b = (e >> 10) / LL;
    bf16x8 v = reinterpret_cast<bf16x8*>(yb)[idx];
    const f32x4* gp = (const f32x4*)(g + b * 1024 + ch);
    f32x4 g0 = gp[0], g1 = gp[1];
    #pragma unroll
    for (int j = 0; j < 4; ++j) v[j] = (__bf16)((float)v[j] * g0[j]);
    #pragma unroll
    for (int j = 0; j < 4; ++j) v[4 + j] = (__bf16)((float)v[4 + j] * g1[j]);
    reinterpret_cast<bf16x8*>(yb)[idx] = v;
}

// ---------------------------------------------------------------------------
// gemm8: out = y @ W_out^T (M=3600,N=256,K=1024), KS=2 combined in LDS.
// ---------------------------------------------------------------------------
__launch_bounds__(256)
__global__ void gemm8_comb(const __bf16* __restrict__ A, const __bf16* __restrict__ B,
                           float* __restrict__ out)
{
    constexpr int WM = 3, WN = 2, K = 1024, KSL = 512, nk = KSL >> 5;  // 16 chunks
    constexpr int N = DMODEL, ntN = N / (16 * WN);                      // 8
    __shared__ float lds[2][2][48 * 32];
    int wv = threadIdx.x >> 6;
    int tLoc = wv >> 1, ks = wv & 1;
    int tIdx = blockIdx.x * 2 + tLoc;          // 600 tiles
    int tm = tIdx / ntN, tn = tIdx % ntN;
    int kOff = ks * KSL;
    int lane = threadIdx.x & 63, q = lane >> 4, r = lane & 15;

    const bf16x8* Ar[WM]; const bf16x8* Br[WN];
    #pragma unroll
    for (int mi = 0; mi < WM; ++mi)
        Ar[mi] = (const bf16x8*)(A + (size_t)(tm * 48 + mi * 16 + r) * K + kOff);
    #pragma unroll
    for (int ni = 0; ni < WN; ++ni)
        Br[ni] = (const bf16x8*)(B + (size_t)(tn * 32 + ni * 16 + r) * K + kOff);
    f32x4 acc[WM][WN];
    #pragma unroll
    for (int mi = 0; mi < WM; ++mi)
        #pragma unroll
        for (int ni = 0; ni < WN; ++ni) acc[mi][ni] = (f32x4){0.f,0.f,0.f,0.f};

    #pragma unroll
    for (int kk = 0; kk < nk; ++kk) {
        int idx = kk * 4 + q;
        bf16x8 av[WM], bv[WN];
        #pragma unroll
        for (int mi = 0; mi < WM; ++mi) av[mi] = Ar[mi][idx];
        #pragma unroll
        for (int ni = 0; ni < WN; ++ni) bv[ni] = Br[ni][idx];
        #pragma unroll
        for (int mi = 0; mi < WM; ++mi)
            #pragma unroll
            for (int ni = 0; ni < WN; ++ni)
                acc[mi][ni] = __builtin_amdgcn_mfma_f32_16x16x32_bf16(av[mi], bv[ni], acc[mi][ni], 0, 0, 0);
    }
    #pragma unroll
    for (int mi = 0; mi < WM; ++mi)
        #pragma unroll
        for (int ni = 0; ni < WN; ++ni) {
            int col = ni * 16 + r;
            #pragma unroll
            for (int i = 0; i < 4; ++i)
                lds[tLoc][ks][(mi * 16 + q * 4 + i) * 32 + col] = acc[mi][ni][i];
        }
    __syncthreads();
    // packed 2*1536 range; tl = e/1536 (round-9 bug fixed in r10)
    for (int e = threadIdx.x; e < 2 * 1536; e += 256) {
        int tl = (e >= 1536) ? 1 : 0;
        int idx = e - tl * 1536;
        int row = idx >> 5, col = idx & 31;
        int tg = blockIdx.x * 2 + tl;
        int gm = (tg / ntN) * 48 + row, gn = (tg % ntN) * 32 + col;
        out[(size_t)gm * N + gn] = lds[tl][0][idx] + lds[tl][1][idx];
    }
}

// ---------------------------------------------------------------------------
extern "C" void kernel_launch(void* const* d_in, const int* in_sizes, int n_in,
                              void* d_out, int out_size, void* d_ws, size_t ws_size,
                              hipStream_t stream)
{
    const float* hidden  = (const float*)d_in[0];
    const float* W_in    = (const float*)d_in[1];
    const float* W_xproj = (const float*)d_in[2];
    const float* W_dt    = (const float*)d_in[3];
    const float* b_dt    = (const float*)d_in[4];
    const float* A_log_f = (const float*)d_in[5];
    const float* A_log_b = (const float*)d_in[6];
    const float* D_f     = (const float*)d_in[7];
    const float* D_b     = (const float*)d_in[8];
    const float* W_glob  = (const float*)d_in[9];
    const float* b_glob  = (const float*)d_in[10];
    const float* W_gate  = (const float*)d_in[11];
    const float* b_gate  = (const float*)d_in[12];
    const float* W_out   = (const float*)d_in[13];
    float* out = (float*)d_out;

    // workspace (~45 MB)
    char* w = (char*)d_ws;
    __bf16* xb    = (__bf16*)w; w += (size_t)BL * DINNER * 2;            // 3.69 MB
    __bf16* zb    = (__bf16*)w; w += (size_t)BL * DINNER * 2;            // 3.69 MB
    float* dtBC   = (float*)w;  w += (size_t)BL * 48 * 4;                // 0.69 MB
    __bf16* dtb   = (__bf16*)w; w += (size_t)BL * DINNER * 2;            // 3.69 MB
    __bf16* yb    = (__bf16*)w; w += (size_t)BL * 2 * DINNER * 2;        // 7.37 MB
    float* partial= (float*)w;  w += (size_t)BB * NC * 1024 * 4;         // 1.23 MB
    float* ymean  = (float*)w;  w += (size_t)BB * 1024 * 4;
    float* t1     = (float*)w;  w += (size_t)BB * 1024 * 4;
    float* gbuf   = (float*)w;  w += (size_t)BB * 1024 * 4;
    __bf16* hh    = (__bf16*)w; w += (size_t)N_HID * 2;                  // 1.84 MB
    __bf16* wih   = (__bf16*)w; w += (size_t)N_WIN * 2;
    __bf16* wxh   = (__bf16*)w; w += (size_t)N_WXP * 2;
    __bf16* woh   = (__bf16*)w; w += (size_t)N_WOUT * 2;
    __bf16* wgb   = (__bf16*)w; w += (size_t)N_WG * 2;                   // 2.1 MB
    __bf16* wtb   = (__bf16*)w; w += (size_t)N_WG * 2;                   // 2.1 MB
    float* sdtBuf = (float*)w;  w += (size_t)BB * 2 * NC * DINNER * 4;   // 1.23 MB
    __bf16* Qbuf  = (__bf16*)w; w += (size_t)BB * 2 * NC * DSTATE * DINNER * 2;  // 9.83 MB

    // 0) bf16 conversion of hidden + weights
    cvt_inputs<<<dim3((N_TOT + 255) / 256), dim3(256), 0, stream>>>(
        hidden, W_in, W_xproj, W_out, W_glob, W_gate, hh, wih, wxh, woh, wgb, wtb);
    // 1) xz = hidden @ W_in^T, fused silu (2400 waves)
    gemm_silu<<<dim3(600), dim3(256), 0, stream>>>(hh, wih, xb, zb);
    // 2) x_dbl + dt, fused (225 blocks)
    gemm2_dt<<<dim3(225), dim3(256), 0, stream>>>(xb, wxh, W_dt, b_dt, dtBC, dtb);
    // 3) chunked scan (4800 waves/pass); P stored as scalar sdt, Q/H0 bf16
    scan_pass1<<<dim3(NC * 4, 2, BB), dim3(128), 0, stream>>>(
        dtb, xb, dtBC, A_log_f, A_log_b, sdtBuf, Qbuf);
    scan_stitch<<<dim3(256), dim3(256), 0, stream>>>(sdtBuf, A_log_f, A_log_b, Qbuf);
    scan_pass3<<<dim3(NC * 4, 2, BB), dim3(128), 0, stream>>>(
        dtb, xb, dtBC, A_log_f, A_log_b, D_f, D_b, zb, Qbuf, yb, partial);
    // 4) mean
    mean2<<<dim3(16), dim3(256), 0, stream>>>(partial, ymean);
    // 5) gating (bf16 weights)
    gemv1024<0><<<dim3(1024), dim3(256), 0, stream>>>(ymean, wgb, b_glob, t1);
    gemv1024<1><<<dim3(1024), dim3(256), 0, stream>>>(t1, wtb, b_gate, gbuf);
    // 6) y *= g (bf16 in place)
    scale_y<<<dim3(BL * 1024 / 8 / 256), dim3(256), 0, stream>>>(yb, gbuf);
    // 7) out = y @ W_out^T, KS=2 LDS-combined (300 blocks)
    gemm8_comb<<<dim3(300), dim3(256), 0, stream>>>(yb, woh, out);
}

// Round 15
// 208.183 us; speedup vs baseline: 4.2867x; 1.0551x over previous
//
#include <hip/hip_runtime.h>
#include <hip/hip_bf16.h>

// Problem constants
#define BB 4
#define LL 900
#define DMODEL 256
#define DSTATE 16
#define DINNER 512
#define DTRANK 16
#define BL (BB*LL)          // 3600
#define NC 75               // scan chunks
#define LC 12               // steps per chunk; NC*LC == LL

typedef __bf16 bf16x8 __attribute__((ext_vector_type(8)));
typedef __bf16 bf16x4 __attribute__((ext_vector_type(4)));
typedef float f32x4 __attribute__((ext_vector_type(4)));

__device__ __forceinline__ float silu_f(float v) { return v / (1.f + __expf(-v)); }

// ---------------------------------------------------------------------------
// One-time bf16 conversion of GEMM operands + zero-init of ymean accumulator
// (gemv weights stay fp32: each element is read exactly once — pre-conversion
//  was pure overhead)
// ---------------------------------------------------------------------------
#define N_HID  (BL*DMODEL)             // 921600
#define N_WIN  (2*DINNER*DMODEL)       // 262144
#define N_WXP  (48*DINNER)             // 24576
#define N_WOUT (DMODEL*2*DINNER)       // 262144
#define N_TOT  (N_HID+N_WIN+N_WXP+N_WOUT)
__global__ void cvt_inputs(const float* __restrict__ hidden, const float* __restrict__ Win,
                           const float* __restrict__ Wxp, const float* __restrict__ Wout,
                           __bf16* __restrict__ hh, __bf16* __restrict__ wih,
                           __bf16* __restrict__ wxh, __bf16* __restrict__ woh,
                           float* __restrict__ ymean)
{
    int idx = blockIdx.x * 256 + threadIdx.x;
    if (idx < BB * 1024) ymean[idx] = 0.f;     // accumulator for pass3 atomics
    if (idx >= N_TOT) return;
    const float* src; __bf16* dst; int off;
    if (idx < N_HID)                        { src = hidden; dst = hh;  off = idx; }
    else if (idx < N_HID+N_WIN)             { src = Win;    dst = wih; off = idx - N_HID; }
    else if (idx < N_HID+N_WIN+N_WXP)       { src = Wxp;    dst = wxh; off = idx - N_HID - N_WIN; }
    else                                    { src = Wout;   dst = woh; off = idx - N_HID - N_WIN - N_WXP; }
    dst[off] = (__bf16)src[off];
}

// ---------------------------------------------------------------------------
// gemm1: xz = hidden @ W_in^T (M=3600,N=1024,K=256), bf16 MFMA, fused silu.
// Wave tile 48x32 (WM=3,WN=2); 2400 waves.
// ---------------------------------------------------------------------------
__launch_bounds__(256)
__global__ void gemm_silu(const __bf16* __restrict__ A, const __bf16* __restrict__ B,
                          __bf16* __restrict__ xb, __bf16* __restrict__ zb)
{
    constexpr int WM = 3, WN = 2, K = 256, nk = K >> 5;
    constexpr int M = BL, N = 2 * DINNER;
    int wave = (blockIdx.x * 256 + threadIdx.x) >> 6;
    int ntN = N / (16 * WN);
    if (wave >= (M / (16 * WM)) * ntN) return;
    int tm = wave / ntN, tn = wave % ntN;
    int lane = threadIdx.x & 63, q = lane >> 4, r = lane & 15;

    const bf16x8* Ar[WM]; const bf16x8* Br[WN];
    #pragma unroll
    for (int mi = 0; mi < WM; ++mi)
        Ar[mi] = (const bf16x8*)(A + (size_t)(tm * 48 + mi * 16 + r) * K);
    #pragma unroll
    for (int ni = 0; ni < WN; ++ni)
        Br[ni] = (const bf16x8*)(B + (size_t)(tn * 32 + ni * 16 + r) * K);
    f32x4 acc[WM][WN];
    #pragma unroll
    for (int mi = 0; mi < WM; ++mi)
        #pragma unroll
        for (int ni = 0; ni < WN; ++ni) acc[mi][ni] = (f32x4){0.f,0.f,0.f,0.f};

    #pragma unroll
    for (int kk = 0; kk < nk; ++kk) {
        int idx = kk * 4 + q;
        bf16x8 av[WM], bv[WN];
        #pragma unroll
        for (int mi = 0; mi < WM; ++mi) av[mi] = Ar[mi][idx];
        #pragma unroll
        for (int ni = 0; ni < WN; ++ni) bv[ni] = Br[ni][idx];
        #pragma unroll
        for (int mi = 0; mi < WM; ++mi)
            #pragma unroll
            for (int ni = 0; ni < WN; ++ni)
                acc[mi][ni] = __builtin_amdgcn_mfma_f32_16x16x32_bf16(av[mi], bv[ni], acc[mi][ni], 0, 0, 0);
    }
    #pragma unroll
    for (int mi = 0; mi < WM; ++mi)
        #pragma unroll
        for (int ni = 0; ni < WN; ++ni) {
            int col = tn * 32 + ni * 16 + r;
            #pragma unroll
            for (int i = 0; i < 4; ++i) {
                int row = tm * 48 + mi * 16 + q * 4 + i;
                float s = silu_f(acc[mi][ni][i]);
                if (col < DINNER) xb[(size_t)row * DINNER + col] = (__bf16)s;
                else              zb[(size_t)row * DINNER + (col - DINNER)] = (__bf16)s;
            }
        }
}

// ---------------------------------------------------------------------------
// gemm2 + dt fused: x_dbl = x @ W_xproj^T (M=3600,N=48,K=512), KS=4 K-split
// combined in LDS, then dt = softplus(...) -> dtb (bf16)
// ---------------------------------------------------------------------------
__launch_bounds__(256)
__global__ void gemm2_dt(const __bf16* __restrict__ A, const __bf16* __restrict__ B,
                         const float* __restrict__ Wdt, const float* __restrict__ bdt,
                         float* __restrict__ dtBC, __bf16* __restrict__ dtb)
{
    constexpr int WN = 3, K = 512, KSL = 128, nk = KSL >> 5;   // 4 chunks
    __shared__ float lds[4][16 * 48];
    int tm = blockIdx.x;                       // 225 tiles (16 rows each)
    int wv = threadIdx.x >> 6, kOff = wv * KSL;
    int lane = threadIdx.x & 63, q = lane >> 4, r = lane & 15;

    const bf16x8* Ar = (const bf16x8*)(A + (size_t)(tm * 16 + r) * K + kOff);
    const bf16x8* Br[WN];
    #pragma unroll
    for (int ni = 0; ni < WN; ++ni)
        Br[ni] = (const bf16x8*)(B + (size_t)(ni * 16 + r) * K + kOff);
    f32x4 acc[WN];
    #pragma unroll
    for (int ni = 0; ni < WN; ++ni) acc[ni] = (f32x4){0.f,0.f,0.f,0.f};

    #pragma unroll
    for (int kk = 0; kk < nk; ++kk) {
        int idx = kk * 4 + q;
        bf16x8 av = Ar[idx];
        #pragma unroll
        for (int ni = 0; ni < WN; ++ni)
            acc[ni] = __builtin_amdgcn_mfma_f32_16x16x32_bf16(av, Br[ni][idx], acc[ni], 0, 0, 0);
    }
    #pragma unroll
    for (int ni = 0; ni < WN; ++ni) {
        int col = ni * 16 + r;
        #pragma unroll
        for (int i = 0; i < 4; ++i)
            lds[wv][(q * 4 + i) * 48 + col] = acc[ni][i];
    }
    __syncthreads();
    for (int e = threadIdx.x; e < 16 * 48; e += 256) {
        float s = lds[0][e] + lds[1][e] + lds[2][e] + lds[3][e];
        lds[0][e] = s;
        int row = e / 48, col = e % 48;
        dtBC[(size_t)(tm * 16 + row) * 48 + col] = s;
    }
    __syncthreads();
    for (int it = 0; it < 32; ++it) {
        int e = threadIdx.x + it * 256;        // 8192
        int row = e >> 9, d = e & 511;
        const float* wr = Wdt + (size_t)d * DTRANK;
        float s = bdt[d];
        #pragma unroll
        for (int k = 0; k < DTRANK; ++k) s = fmaf(lds[0][row * 48 + k], wr[k], s);
        float dtv = (s > 15.f) ? s : __logf(1.f + __expf(s));
        dtb[(size_t)(tm * 16 + row) * DINNER + d] = (__bf16)dtv;
    }
}

// ---------------------------------------------------------------------------
// Scan pass 1: per-chunk zero-init run -> Q (end state, bf16), sdt (scalar).
// Q layout: [bd][c][n][d] (d fastest). sdt: [bd][c][d].
// ---------------------------------------------------------------------------
__global__ void scan_pass1(const __bf16* __restrict__ dtb,
                           const __bf16* __restrict__ xb,
                           const float* __restrict__ dtBC,
                           const float* __restrict__ AlogF, const float* __restrict__ AlogB,
                           float* __restrict__ sdtBuf, __bf16* __restrict__ Qbuf)
{
    int b = blockIdx.z, dir = blockIdx.y;
    int c = blockIdx.x >> 2, dgrp = blockIdx.x & 3;
    int d = dgrp * 128 + threadIdx.x;
    const float* Alog = dir ? AlogB : AlogF;
    float a2[DSTATE];
    #pragma unroll
    for (int n = 0; n < DSTATE; ++n) a2[n] = -__expf(Alog[d * DSTATE + n]) * 1.44269504f;
    float h[DSTATE];
    #pragma unroll
    for (int n = 0; n < DSTATE; ++n) h[n] = 0.f;
    float sdt = 0.f;

    #pragma unroll 4
    for (int il = 0; il < LC; ++il) {
        int i = c * LC + il;
        int l = dir ? (LL - 1 - i) : i;
        size_t base = (size_t)b * LL + l;
        float dtv = (float)dtb[base * DINNER + d];
        float u = (float)xb[base * DINNER + d];
        float du = dtv * u;
        const f32x4* Bp = (const f32x4*)(dtBC + base * 48 + DTRANK);
        f32x4 Bq[4];
        #pragma unroll
        for (int j = 0; j < 4; ++j) Bq[j] = Bp[j];
        sdt += dtv;
        #pragma unroll
        for (int n = 0; n < DSTATE; ++n)
            h[n] = fmaf(exp2f(dtv * a2[n]), h[n], du * Bq[n >> 2][n & 3]);
    }
    int bd = b * 2 + dir;
    sdtBuf[((size_t)bd * NC + c) * DINNER + d] = sdt;
    size_t o = (((size_t)bd * NC + c) * DSTATE) * DINNER + d;
    #pragma unroll
    for (int n = 0; n < DSTATE; ++n)
        Qbuf[o + (size_t)n * DINNER] = (__bf16)h[n];
}

// Pass 2: stitch in place on Qbuf (H0 overwrites Q); P recomputed from sdt.
__global__ void scan_stitch(const float* __restrict__ sdtBuf,
                            const float* __restrict__ AlogF, const float* __restrict__ AlogB,
                            __bf16* __restrict__ Qbuf)
{
    int idx = blockIdx.x * 256 + threadIdx.x;   // 65536
    int bd = idx >> 13;
    int rem = idx & 8191;           // n*512 + d
    int n = rem >> 9, d = rem & 511;
    const float* Alog = (bd & 1) ? AlogB : AlogF;
    float a2 = -__expf(Alog[d * DSTATE + n]) * 1.44269504f;
    size_t qbase = (size_t)bd * NC * 8192 + rem;
    size_t sbase = (size_t)bd * NC * DINNER + d;
    float H = 0.f;
    for (int cb = 0; cb < NC; cb += 15) {
        float Qv[15], Sv[15];
        #pragma unroll
        for (int j = 0; j < 15; ++j) {
            Qv[j] = (float)Qbuf[qbase + (size_t)(cb + j) * 8192];
            Sv[j] = sdtBuf[sbase + (size_t)(cb + j) * DINNER];
        }
        #pragma unroll
        for (int j = 0; j < 15; ++j) {
            Qbuf[qbase + (size_t)(cb + j) * 8192] = (__bf16)H;   // H0 for chunk
            H = fmaf(exp2f(Sv[j] * a2), H, Qv[j]);
        }
    }
}

// Pass 3: re-run chunk from true initial state (bf16 H0 in Qbuf); emit y;
// accumulate the L-mean numerator straight into ymean via atomics.
__global__ void scan_pass3(const __bf16* __restrict__ dtb,
                           const __bf16* __restrict__ xb,
                           const float* __restrict__ dtBC,
                           const float* __restrict__ AlogF, const float* __restrict__ AlogB,
                           const float* __restrict__ Df, const float* __restrict__ Db,
                           const __bf16* __restrict__ zb,
                           const __bf16* __restrict__ H0buf,
                           __bf16* __restrict__ yb,        // [B,L,1024]
                           float* __restrict__ ymean)      // [B,1024] (pre-zeroed)
{
    int b = blockIdx.z, dir = blockIdx.y;
    int c = blockIdx.x >> 2, dgrp = blockIdx.x & 3;
    int d = dgrp * 128 + threadIdx.x;
    const float* Alog = dir ? AlogB : AlogF;
    float a2[DSTATE];
    #pragma unroll
    for (int n = 0; n < DSTATE; ++n) a2[n] = -__expf(Alog[d * DSTATE + n]) * 1.44269504f;
    float Dd = dir ? Db[d] : Df[d];
    size_t o = (((size_t)(b * 2 + dir) * NC + c) * DSTATE) * DINNER + d;
    float h[DSTATE];
    #pragma unroll
    for (int n = 0; n < DSTATE; ++n) h[n] = (float)H0buf[o + (size_t)n * DINNER];
    float ysum = 0.f;

    #pragma unroll 4
    for (int il = 0; il < LC; ++il) {
        int i = c * LC + il;
        int l = dir ? (LL - 1 - i) : i;
        size_t base = (size_t)b * LL + l;
        float dtv = (float)dtb[base * DINNER + d];
        float u = (float)xb[base * DINNER + d];
        float du = dtv * u;
        const f32x4* Bp = (const f32x4*)(dtBC + base * 48 + DTRANK);
        f32x4 Bq[4], Cq[4];
        #pragma unroll
        for (int j = 0; j < 4; ++j) Bq[j] = Bp[j];
        #pragma unroll
        for (int j = 0; j < 4; ++j) Cq[j] = Bp[4 + j];
        float p = 0.f;
        #pragma unroll
        for (int n = 0; n < DSTATE; ++n) {
            h[n] = fmaf(exp2f(dtv * a2[n]), h[n], du * Bq[n >> 2][n & 3]);
            p = fmaf(h[n], Cq[n >> 2][n & 3], p);
        }
        float zg = (float)zb[base * DINNER + d];
        float yv = (p + Dd * u) * zg;
        size_t yo = base * (2 * DINNER) + dir * DINNER + d;
        yb[yo] = (__bf16)yv;
        ysum += yv;
    }
    atomicAdd(&ymean[b * 1024 + dir * DINNER + d], ysum);
}

// gemv: one wave per (b,j); 4096 waves; fp32 weights (read once each).
// vout = [sigmoid]( dot(vin, W[j]) * scl + bias[j] )
template<int SIG>
__global__ void gemv1024(const float* __restrict__ vin,
                         const float* __restrict__ W,
                         const float* __restrict__ bias,
                         float* __restrict__ vout, float scl)
{
    int wv = (blockIdx.x * blockDim.x + threadIdx.x) >> 6;
    int b = wv >> 10, j = wv & 1023;
    int lane = threadIdx.x & 63;
    const float* wr = W + (size_t)j * 1024;
    const float* vr = vin + (size_t)b * 1024;
    float s = 0.f;
    for (int k = lane; k < 1024; k += 64) s = fmaf(vr[k], wr[k], s);
    #pragma unroll
    for (int o = 32; o; o >>= 1) s += __shfl_xor(s, o);
    if (lane == 0) {
        s = s * scl + bias[j];
        vout[wv] = SIG ? (1.f / (1.f + __expf(-s))) : s;
    }
}

// ---------------------------------------------------------------------------
// gemm8: out = (y ∘ g) @ W_out^T (M=3600,N=256,K=1024), KS=4 LDS-combined.
// One 48x32 tile per block; 4 waves = 4 K-slices of 256. g applied to the
// A fragment in fp32 right before MFMA (replaces the scale_y kernel).
// ---------------------------------------------------------------------------
__launch_bounds__(256)
__global__ void gemm8_comb(const __bf16* __restrict__ A, const __bf16* __restrict__ B,
                           const float* __restrict__ g,   // [BB,1024]
                           float* __restrict__ out)
{
    constexpr int WM = 3, WN = 2, K = 1024, KSL = 256, nk = KSL >> 5;  // 8 chunks
    constexpr int N = DMODEL, ntN = N / (16 * WN);                      // 8
    __shared__ float lds[4][48 * 32];
    int ks = threadIdx.x >> 6;
    int tIdx = blockIdx.x;                     // 600 tiles
    int tm = tIdx / ntN, tn = tIdx % ntN;
    int kOff = ks * KSL;
    int lane = threadIdx.x & 63, q = lane >> 4, r = lane & 15;

    const bf16x8* Ar[WM]; const bf16x8* Br[WN];
    const float* gp[WM];
    #pragma unroll
    for (int mi = 0; mi < WM; ++mi) {
        int grow = tm * 48 + mi * 16 + r;
        Ar[mi] = (const bf16x8*)(A + (size_t)grow * K + kOff);
        gp[mi] = g + (grow / LL) * 1024 + kOff;
    }
    #pragma unroll
    for (int ni = 0; ni < WN; ++ni)
        Br[ni] = (const bf16x8*)(B + (size_t)(tn * 32 + ni * 16 + r) * K + kOff);
    f32x4 acc[WM][WN];
    #pragma unroll
    for (int mi = 0; mi < WM; ++mi)
        #pragma unroll
        for (int ni = 0; ni < WN; ++ni) acc[mi][ni] = (f32x4){0.f,0.f,0.f,0.f};

    #pragma unroll
    for (int kk = 0; kk < nk; ++kk) {
        int idx = kk * 4 + q;
        bf16x8 av[WM], bv[WN];
        #pragma unroll
        for (int mi = 0; mi < WM; ++mi) {
            bf16x8 a = Ar[mi][idx];
            const f32x4* gv = (const f32x4*)(gp[mi] + idx * 8);
            f32x4 g0 = gv[0], g1 = gv[1];
            #pragma unroll
            for (int j = 0; j < 4; ++j) a[j] = (__bf16)((float)a[j] * g0[j]);
            #pragma unroll
            for (int j = 0; j < 4; ++j) a[4 + j] = (__bf16)((float)a[4 + j] * g1[j]);
            av[mi] = a;
        }
        #pragma unroll
        for (int ni = 0; ni < WN; ++ni) bv[ni] = Br[ni][idx];
        #pragma unroll
        for (int mi = 0; mi < WM; ++mi)
            #pragma unroll
            for (int ni = 0; ni < WN; ++ni)
                acc[mi][ni] = __builtin_amdgcn_mfma_f32_16x16x32_bf16(av[mi], bv[ni], acc[mi][ni], 0, 0, 0);
    }
    #pragma unroll
    for (int mi = 0; mi < WM; ++mi)
        #pragma unroll
        for (int ni = 0; ni < WN; ++ni) {
            int col = ni * 16 + r;
            #pragma unroll
            for (int i = 0; i < 4; ++i)
                lds[ks][(mi * 16 + q * 4 + i) * 32 + col] = acc[mi][ni][i];
        }
    __syncthreads();
    for (int e = threadIdx.x; e < 1536; e += 256) {
        int row = e >> 5, col = e & 31;
        int gm = tm * 48 + row, gn = tn * 32 + col;
        out[(size_t)gm * N + gn] = lds[0][e] + lds[1][e] + lds[2][e] + lds[3][e];
    }
}

// ---------------------------------------------------------------------------
extern "C" void kernel_launch(void* const* d_in, const int* in_sizes, int n_in,
                              void* d_out, int out_size, void* d_ws, size_t ws_size,
                              hipStream_t stream)
{
    const float* hidden  = (const float*)d_in[0];
    const float* W_in    = (const float*)d_in[1];
    const float* W_xproj = (const float*)d_in[2];
    const float* W_dt    = (const float*)d_in[3];
    const float* b_dt    = (const float*)d_in[4];
    const float* A_log_f = (const float*)d_in[5];
    const float* A_log_b = (const float*)d_in[6];
    const float* D_f     = (const float*)d_in[7];
    const float* D_b     = (const float*)d_in[8];
    const float* W_glob  = (const float*)d_in[9];
    const float* b_glob  = (const float*)d_in[10];
    const float* W_gate  = (const float*)d_in[11];
    const float* b_gate  = (const float*)d_in[12];
    const float* W_out   = (const float*)d_in[13];
    float* out = (float*)d_out;

    // workspace (~40 MB)
    char* w = (char*)d_ws;
    __bf16* xb    = (__bf16*)w; w += (size_t)BL * DINNER * 2;            // 3.69 MB
    __bf16* zb    = (__bf16*)w; w += (size_t)BL * DINNER * 2;            // 3.69 MB
    float* dtBC   = (float*)w;  w += (size_t)BL * 48 * 4;                // 0.69 MB
    __bf16* dtb   = (__bf16*)w; w += (size_t)BL * DINNER * 2;            // 3.69 MB
    __bf16* yb    = (__bf16*)w; w += (size_t)BL * 2 * DINNER * 2;        // 7.37 MB
    float* ymean  = (float*)w;  w += (size_t)BB * 1024 * 4;
    float* t1     = (float*)w;  w += (size_t)BB * 1024 * 4;
    float* gbuf   = (float*)w;  w += (size_t)BB * 1024 * 4;
    __bf16* hh    = (__bf16*)w; w += (size_t)N_HID * 2;                  // 1.84 MB
    __bf16* wih   = (__bf16*)w; w += (size_t)N_WIN * 2;
    __bf16* wxh   = (__bf16*)w; w += (size_t)N_WXP * 2;
    __bf16* woh   = (__bf16*)w; w += (size_t)N_WOUT * 2;
    float* sdtBuf = (float*)w;  w += (size_t)BB * 2 * NC * DINNER * 4;   // 1.23 MB
    __bf16* Qbuf  = (__bf16*)w; w += (size_t)BB * 2 * NC * DSTATE * DINNER * 2;  // 9.83 MB

    // 0) bf16 conversion of hidden + GEMM weights; zero ymean
    cvt_inputs<<<dim3((N_TOT + 255) / 256), dim3(256), 0, stream>>>(
        hidden, W_in, W_xproj, W_out, hh, wih, wxh, woh, ymean);
    // 1) xz = hidden @ W_in^T, fused silu (2400 waves)
    gemm_silu<<<dim3(600), dim3(256), 0, stream>>>(hh, wih, xb, zb);
    // 2) x_dbl + dt, fused (225 blocks)
    gemm2_dt<<<dim3(225), dim3(256), 0, stream>>>(xb, wxh, W_dt, b_dt, dtBC, dtb);
    // 3) chunked scan (4800 waves/pass); pass3 accumulates ymean via atomics
    scan_pass1<<<dim3(NC * 4, 2, BB), dim3(128), 0, stream>>>(
        dtb, xb, dtBC, A_log_f, A_log_b, sdtBuf, Qbuf);
    scan_stitch<<<dim3(256), dim3(256), 0, stream>>>(sdtBuf, A_log_f, A_log_b, Qbuf);
    scan_pass3<<<dim3(NC * 4, 2, BB), dim3(128), 0, stream>>>(
        dtb, xb, dtBC, A_log_f, A_log_b, D_f, D_b, zb, Qbuf, yb, ymean);
    // 4) gating (mean folded in as x(1/LL); fp32 weights)
    gemv1024<0><<<dim3(1024), dim3(256), 0, stream>>>(ymean, W_glob, b_glob, t1, 1.f / (float)LL);
    gemv1024<1><<<dim3(1024), dim3(256), 0, stream>>>(t1, W_gate, b_gate, gbuf, 1.f);
    // 5) out = (y ∘ g) @ W_out^T, KS=4 LDS-combined (600 blocks); g fused in
    gemm8_comb<<<dim3(600), dim3(256), 0, stream>>>(yb, woh, gbuf, out);
}